// Round 1
// baseline (2300.437 us; speedup 1.0000x reference)
//
#include <hip/hip_runtime.h>
#include <hip/hip_fp16.h>

#define D 1024
#define LOG2D 10
#define S_LEN 4096
#define BATCH 4
#define NROWS (BATCH * S_LEN) /* 16384 */
#define PI_F 3.14159265358979323846f

__device__ __forceinline__ float2 cmul(float2 a, float2 b) {
    return make_float2(a.x * b.x - a.y * b.y, a.x * b.y + a.y * b.x);
}

// Twiddle table: Wt[j] = exp(-i*pi*j/512), j in [0,512)
__device__ __forceinline__ void build_twiddles(float2* Wt, int tid) {
    for (int j = tid; j < D / 2; j += 256) {
        float a = PI_F * (float)j / (float)(D / 2);
        Wt[j] = make_float2(cosf(a), -sinf(a));
    }
}

// In-LDS radix-2 Stockham FFT, length 1024, 256 threads, natural order in/out.
// Result ends in bufA. dir=+1: forward (exp(-i..)); dir=-1: inverse (unscaled).
__device__ void fft1024(float2* bufA, float2* bufB, const float2* Wt, float dir, int tid) {
    float2* src = bufA;
    float2* dst = bufB;
#pragma unroll
    for (int s = 0; s < LOG2D; ++s) {
        __syncthreads();
        const int m = 1 << s;
#pragma unroll
        for (int h = 0; h < 2; ++h) {
            const int i = tid + (h << 8);  // 0..511
            const int k = i & (m - 1);
            const int jb = i >> s;
            float2 a = src[i];
            float2 bv = src[i + D / 2];
            float2 tw = Wt[k << (LOG2D - 1 - s)];
            const float wy = dir * tw.y;
            float2 wb = make_float2(tw.x * bv.x - wy * bv.y, tw.x * bv.y + wy * bv.x);
            const int o = (jb << (s + 1)) + k;
            dst[o]     = make_float2(a.x + wb.x, a.y + wb.y);
            dst[o + m] = make_float2(a.x - wb.x, a.y - wb.y);
        }
        float2* t = src; src = dst; dst = t;
    }
    __syncthreads();
}

// C[m,n] = tanh( sum_k X[m,k]*W[n,k] + bias[n] ), stored fp16.
// 64x64 tile, BK=16, 256 threads, 4x4 per thread. blockIdx.z selects matrix pair.
__global__ __launch_bounds__(256) void gemm_tanh2(
    const float* __restrict__ X,
    const float* __restrict__ Wa, const float* __restrict__ ba, __half* __restrict__ Oa,
    const float* __restrict__ Wb, const float* __restrict__ bb, __half* __restrict__ Ob)
{
    const float* W    = blockIdx.z ? Wb : Wa;
    const float* bias = blockIdx.z ? bb : ba;
    __half* O         = blockIdx.z ? Ob : Oa;

    const int m0 = blockIdx.y * 64;
    const int n0 = blockIdx.x * 64;

    __shared__ __align__(16) float Xs[16][64];
    __shared__ __align__(16) float Ws[16][64];

    const int tid = threadIdx.x;
    const int tx = tid & 15;       // n micro index
    const int ty = tid >> 4;       // m micro index
    const int lrow = tid >> 2;     // 0..63 loader row
    const int lk = (tid & 3) << 2; // 0,4,8,12 loader k quad

    float acc[4][4];
#pragma unroll
    for (int i = 0; i < 4; ++i)
#pragma unroll
        for (int j = 0; j < 4; ++j) acc[i][j] = 0.0f;

    for (int k0 = 0; k0 < 1024; k0 += 16) {
        float4 xa = *(const float4*)(X + (size_t)(m0 + lrow) * 1024 + k0 + lk);
        float4 wa = *(const float4*)(W + (size_t)(n0 + lrow) * 1024 + k0 + lk);
        __syncthreads();
        Xs[lk + 0][lrow] = xa.x; Xs[lk + 1][lrow] = xa.y;
        Xs[lk + 2][lrow] = xa.z; Xs[lk + 3][lrow] = xa.w;
        Ws[lk + 0][lrow] = wa.x; Ws[lk + 1][lrow] = wa.y;
        Ws[lk + 2][lrow] = wa.z; Ws[lk + 3][lrow] = wa.w;
        __syncthreads();
#pragma unroll
        for (int kk = 0; kk < 16; ++kk) {
            float4 av = ((const float4*)Xs[kk])[ty];
            float4 bv = ((const float4*)Ws[kk])[tx];
            float am[4] = {av.x, av.y, av.z, av.w};
            float bn[4] = {bv.x, bv.y, bv.z, bv.w};
#pragma unroll
            for (int i = 0; i < 4; ++i)
#pragma unroll
                for (int j = 0; j < 4; ++j) acc[i][j] += am[i] * bn[j];
        }
    }

#pragma unroll
    for (int i = 0; i < 4; ++i) {
        const int m = m0 + ty * 4 + i;
#pragma unroll
        for (int j = 0; j < 4; ++j) {
            const int n = n0 + tx * 4 + j;
            float v = tanhf(acc[i][j] + bias[n]);
            O[(size_t)m * 1024 + n] = __float2half(v);
        }
    }
}

// Per row: Z = FFT(k + i*v); Fk,Fv via Hermitian split; accumulate Fk*Fv into Fs[b].
#define ROWS_PER_BLOCK 8
__global__ __launch_bounds__(256) void bind_accum_kernel(
    const __half* __restrict__ K, const __half* __restrict__ V, float2* __restrict__ Fs)
{
    __shared__ __align__(16) float2 bufA[D];
    __shared__ __align__(16) float2 bufB[D];
    __shared__ __align__(16) float2 Wt[D / 2];
    const int tid = threadIdx.x;
    build_twiddles(Wt, tid);

    const int row0 = blockIdx.x * ROWS_PER_BLOCK;
    const int b = row0 >> 12;  // 4096 rows per batch

    float2 accr[4];
#pragma unroll
    for (int h = 0; h < 4; ++h) accr[h] = make_float2(0.f, 0.f);

    for (int r = 0; r < ROWS_PER_BLOCK; ++r) {
        const size_t base = (size_t)(row0 + r) * D;
        __syncthreads();  // previous iteration's bufA reads must finish
#pragma unroll
        for (int h = 0; h < 4; ++h) {
            const int j = tid + (h << 8);
            bufA[j] = make_float2(__half2float(K[base + j]), __half2float(V[base + j]));
        }
        fft1024(bufA, bufB, Wt, 1.0f, tid);
#pragma unroll
        for (int h = 0; h < 4; ++h) {
            const int j = tid + (h << 8);
            const int j2 = (D - j) & (D - 1);
            float2 Zt = bufA[j];
            float2 Zc = bufA[j2]; Zc.y = -Zc.y;  // conj(Z[N-j])
            float2 Fk = make_float2(0.5f * (Zt.x + Zc.x), 0.5f * (Zt.y + Zc.y));
            float2 Fv = make_float2(0.5f * (Zt.y - Zc.y), -0.5f * (Zt.x - Zc.x));
            float2 P = cmul(Fk, Fv);
            accr[h].x += P.x; accr[h].y += P.y;
        }
    }
#pragma unroll
    for (int h = 0; h < 4; ++h) {
        const int j = tid + (h << 8);
        atomicAdd(&Fs[(size_t)b * D + j].x, accr[h].x);
        atomicAdd(&Fs[(size_t)b * D + j].y, accr[h].y);
    }
}

// Per row: Z = FFT(q + i*r); g = conj(Fq) - |Fr|^2; y = ifft(Fs*g); out = x + Re(y)/D.
__global__ __launch_bounds__(256) void retrieve_kernel(
    const __half* __restrict__ Q, const __half* __restrict__ R,
    const float2* __restrict__ Fs, const float* __restrict__ x, float* __restrict__ out)
{
    __shared__ __align__(16) float2 bufA[D];
    __shared__ __align__(16) float2 bufB[D];
    __shared__ __align__(16) float2 Wt[D / 2];
    const int tid = threadIdx.x;
    build_twiddles(Wt, tid);

    const int row = blockIdx.x;
    const int b = row >> 12;
    const size_t base = (size_t)row * D;

#pragma unroll
    for (int h = 0; h < 4; ++h) {
        const int j = tid + (h << 8);
        bufA[j] = make_float2(__half2float(Q[base + j]), __half2float(R[base + j]));
    }
    fft1024(bufA, bufB, Wt, 1.0f, tid);  // Z in bufA

#pragma unroll
    for (int h = 0; h < 4; ++h) {
        const int j = tid + (h << 8);
        const int j2 = (D - j) & (D - 1);
        float2 Zt = bufA[j];
        float2 Zc = bufA[j2]; Zc.y = -Zc.y;
        float2 Fq = make_float2(0.5f * (Zt.x + Zc.x), 0.5f * (Zt.y + Zc.y));
        float2 Fr = make_float2(0.5f * (Zt.y - Zc.y), -0.5f * (Zt.x - Zc.x));
        float2 g  = make_float2(Fq.x - (Fr.x * Fr.x + Fr.y * Fr.y), -Fq.y);
        float2 Ff = Fs[(size_t)b * D + j];
        bufB[j] = cmul(Ff, g);
    }
    // fft1024 opens with __syncthreads(): bufB writes visible, bufA reads done.
    fft1024(bufB, bufA, Wt, -1.0f, tid);  // result in bufB (unscaled ifft)

    const float inv = 1.0f / (float)D;
#pragma unroll
    for (int h = 0; h < 4; ++h) {
        const int j = tid + (h << 8);
        out[base + j] = x[base + j] + bufB[j].x * inv;
    }
}

extern "C" void kernel_launch(void* const* d_in, const int* in_sizes, int n_in,
                              void* d_out, int out_size, void* d_ws, size_t ws_size,
                              hipStream_t stream) {
    const float* x  = (const float*)d_in[0];
    const float* Wq = (const float*)d_in[1];
    const float* bq = (const float*)d_in[2];
    const float* Wk = (const float*)d_in[3];
    const float* bk = (const float*)d_in[4];
    const float* Wv = (const float*)d_in[5];
    const float* bv = (const float*)d_in[6];
    const float* Wr = (const float*)d_in[7];
    const float* br = (const float*)d_in[8];
    float* out = (float*)d_out;

    // Workspace layout: P0 (32MB fp16: K then Q), P1 (32MB fp16: V then R), Fs (32KB)
    __half* P0 = (__half*)d_ws;
    __half* P1 = (__half*)((char*)d_ws + (size_t)NROWS * D * 2);
    float2* Fs = (float2*)((char*)d_ws + (size_t)NROWS * D * 4);

    hipMemsetAsync(Fs, 0, (size_t)BATCH * D * sizeof(float2), stream);

    dim3 ggrid(1024 / 64, NROWS / 64, 2);
    // K -> P0, V -> P1
    gemm_tanh2<<<ggrid, 256, 0, stream>>>(x, Wk, bk, P0, Wv, bv, P1);
    bind_accum_kernel<<<NROWS / ROWS_PER_BLOCK, 256, 0, stream>>>(P0, P1, Fs);
    // Q -> P0, R -> P1 (reuse)
    gemm_tanh2<<<ggrid, 256, 0, stream>>>(x, Wq, bq, P0, Wr, br, P1);
    retrieve_kernel<<<NROWS, 256, 0, stream>>>(P0, P1, Fs, x, out);
}

// Round 2
// 573.911 us; speedup vs baseline: 4.0084x; 4.0084x over previous
//
#include <hip/hip_runtime.h>
#include <hip/hip_fp16.h>

#define D 1024
#define LOG2D 10
#define S_LEN 4096
#define BATCH 4
#define NROWS (BATCH * S_LEN) /* 16384 */
#define PI_F 3.14159265358979323846f

typedef _Float16 f16x8 __attribute__((ext_vector_type(8)));
typedef float f32x4 __attribute__((ext_vector_type(4)));

__device__ __forceinline__ float2 cmul(float2 a, float2 b) {
    return make_float2(a.x * b.x - a.y * b.y, a.x * b.y + a.y * b.x);
}

__device__ __forceinline__ float fast_tanh(float v) {
    float e = __expf(2.0f * v);
    return 1.0f - 2.0f * __builtin_amdgcn_rcpf(e + 1.0f);
}

__device__ __forceinline__ void g2lds16(const void* g, void* l) {
    __builtin_amdgcn_global_load_lds(
        (const __attribute__((address_space(1))) unsigned int*)g,
        (__attribute__((address_space(3))) unsigned int*)l, 16, 0, 0);
}

// ---------------- fp32 -> fp16 conversion (x and the 4 weight matrices) ----
// Region map: blocks [0,16384) -> x (16M floats), then 1024 blocks per W (1M).
__global__ __launch_bounds__(256) void convert_all(
    const float* __restrict__ x,
    const float* __restrict__ w0, const float* __restrict__ w1,
    const float* __restrict__ w2, const float* __restrict__ w3,
    __half* __restrict__ xh,
    __half* __restrict__ h0, __half* __restrict__ h1,
    __half* __restrict__ h2, __half* __restrict__ h3)
{
    const int b = blockIdx.x;
    const float* s;
    __half* d;
    int li;
    if (b < 16384) { s = x; d = xh; li = b; }
    else {
        int t = b - 16384;
        int r = t >> 10;
        li = t & 1023;
        s = (r == 0) ? w0 : (r == 1) ? w1 : (r == 2) ? w2 : w3;
        d = (r == 0) ? h0 : (r == 1) ? h1 : (r == 2) ? h2 : h3;
    }
    const int idx = li * 256 + threadIdx.x;  // float4 index
    float4 v = ((const float4*)s)[idx];
    __half2 lo = __floats2half2_rn(v.x, v.y);
    __half2 hi = __floats2half2_rn(v.z, v.w);
    ((__half2*)d)[2 * idx + 0] = lo;
    ((__half2*)d)[2 * idx + 1] = hi;
}

// ---------------- MFMA GEMM: O = tanh(Xh * Wh^T + bias), fp16 out ----------
// 128x128 tile, BK=32 halves, 256 thr (4 waves, 2x2 wave grid, 4x4 frags).
// LDS tiles [row][32] halves with XOR chunk swizzle: 16B chunk q of row R
// stored at position q ^ ((R>>1)&3).
__global__ __launch_bounds__(256) void gemm_mfma(
    const __half* __restrict__ Xh,
    const __half* __restrict__ WA, const float* __restrict__ bA, __half* __restrict__ OA,
    const __half* __restrict__ WB, const float* __restrict__ bB, __half* __restrict__ OB)
{
    const __half* W    = blockIdx.z ? WB : WA;
    const float* bias  = blockIdx.z ? bB : bA;
    __half* O          = blockIdx.z ? OB : OA;

    const int m0 = blockIdx.y * 128;
    const int n0 = blockIdx.x * 128;

    __shared__ __align__(16) __half As[128 * 32];
    __shared__ __align__(16) __half Bs[128 * 32];

    const int tid = threadIdx.x;
    const int wave = tid >> 6;
    const int lane = tid & 63;

    // staging: each wave DMAs 2 chunks of 1KB (16 rows x 64B) per tile
    const int srow = lane >> 2;                          // row within 16-row group
    const int schunk = (lane & 3) ^ ((lane >> 3) & 3);   // swizzled global 16B chunk

    const __half* gA[2];
    const __half* gB[2];
    __half* lA[2];
    __half* lB[2];
#pragma unroll
    for (int c = 0; c < 2; ++c) {
        const int rg = (wave * 2 + c) * 16 + srow;
        gA[c] = Xh + (size_t)(m0 + rg) * 1024 + schunk * 8;
        gB[c] = W  + (size_t)(n0 + rg) * 1024 + schunk * 8;
        lA[c] = As + (wave * 2 + c) * 512;
        lB[c] = Bs + (wave * 2 + c) * 512;
    }

    const int wm = (wave & 1) * 64;
    const int wn = (wave >> 1) * 64;
    const int quad = lane >> 4;
    const int l15 = lane & 15;

    int aoff[4], boff[4];
#pragma unroll
    for (int i = 0; i < 4; ++i) {
        const int Ra = wm + i * 16 + l15;
        aoff[i] = Ra * 32 + (quad ^ ((Ra >> 1) & 3)) * 8;
        const int Rb = wn + i * 16 + l15;
        boff[i] = Rb * 32 + (quad ^ ((Rb >> 1) & 3)) * 8;
    }

    f32x4 acc[4][4];
#pragma unroll
    for (int i = 0; i < 4; ++i)
#pragma unroll
        for (int j = 0; j < 4; ++j) acc[i][j] = (f32x4){0.f, 0.f, 0.f, 0.f};

    for (int kt = 0; kt < 32; ++kt) {
        const int kh = kt * 32;
        __syncthreads();
        g2lds16(gA[0] + kh, lA[0]);
        g2lds16(gA[1] + kh, lA[1]);
        g2lds16(gB[0] + kh, lB[0]);
        g2lds16(gB[1] + kh, lB[1]);
        __syncthreads();

        f16x8 af[4], bf[4];
#pragma unroll
        for (int i = 0; i < 4; ++i) af[i] = *(const f16x8*)(As + aoff[i]);
#pragma unroll
        for (int j = 0; j < 4; ++j) bf[j] = *(const f16x8*)(Bs + boff[j]);
#pragma unroll
        for (int i = 0; i < 4; ++i)
#pragma unroll
            for (int j = 0; j < 4; ++j)
                acc[i][j] = __builtin_amdgcn_mfma_f32_16x16x32_f16(af[i], bf[j], acc[i][j], 0, 0, 0);
    }

    // epilogue: C/D frag mapping col=lane&15, row=quad*4+reg
#pragma unroll
    for (int j = 0; j < 4; ++j) {
        const int n = n0 + wn + j * 16 + l15;
        const float bv = bias[n];
#pragma unroll
        for (int i = 0; i < 4; ++i) {
            const int mbase = m0 + wm + i * 16 + quad * 4;
#pragma unroll
            for (int r = 0; r < 4; ++r) {
                float v = fast_tanh(acc[i][j][r] + bv);
                O[(size_t)(mbase + r) * 1024 + n] = __float2half(v);
            }
        }
    }
}

// ---------------- FFT machinery (unchanged from round 1) ------------------
__device__ __forceinline__ void build_twiddles(float2* Wt, int tid) {
    for (int j = tid; j < D / 2; j += 256) {
        float a = PI_F * (float)j / (float)(D / 2);
        Wt[j] = make_float2(cosf(a), -sinf(a));
    }
}

__device__ void fft1024(float2* bufA, float2* bufB, const float2* Wt, float dir, int tid) {
    float2* src = bufA;
    float2* dst = bufB;
#pragma unroll
    for (int s = 0; s < LOG2D; ++s) {
        __syncthreads();
        const int m = 1 << s;
#pragma unroll
        for (int h = 0; h < 2; ++h) {
            const int i = tid + (h << 8);
            const int k = i & (m - 1);
            const int jb = i >> s;
            float2 a = src[i];
            float2 bv = src[i + D / 2];
            float2 tw = Wt[k << (LOG2D - 1 - s)];
            const float wy = dir * tw.y;
            float2 wb = make_float2(tw.x * bv.x - wy * bv.y, tw.x * bv.y + wy * bv.x);
            const int o = (jb << (s + 1)) + k;
            dst[o]     = make_float2(a.x + wb.x, a.y + wb.y);
            dst[o + m] = make_float2(a.x - wb.x, a.y - wb.y);
        }
        float2* t = src; src = dst; dst = t;
    }
    __syncthreads();
}

#define ROWS_PER_BLOCK 8
__global__ __launch_bounds__(256) void bind_accum_kernel(
    const __half* __restrict__ K, const __half* __restrict__ V, float2* __restrict__ Fs)
{
    __shared__ __align__(16) float2 bufA[D];
    __shared__ __align__(16) float2 bufB[D];
    __shared__ __align__(16) float2 Wt[D / 2];
    const int tid = threadIdx.x;
    build_twiddles(Wt, tid);

    const int row0 = blockIdx.x * ROWS_PER_BLOCK;
    const int b = row0 >> 12;

    float2 accr[4];
#pragma unroll
    for (int h = 0; h < 4; ++h) accr[h] = make_float2(0.f, 0.f);

    for (int r = 0; r < ROWS_PER_BLOCK; ++r) {
        const size_t base = (size_t)(row0 + r) * D;
        __syncthreads();
#pragma unroll
        for (int h = 0; h < 4; ++h) {
            const int j = tid + (h << 8);
            bufA[j] = make_float2(__half2float(K[base + j]), __half2float(V[base + j]));
        }
        fft1024(bufA, bufB, Wt, 1.0f, tid);
#pragma unroll
        for (int h = 0; h < 4; ++h) {
            const int j = tid + (h << 8);
            const int j2 = (D - j) & (D - 1);
            float2 Zt = bufA[j];
            float2 Zc = bufA[j2]; Zc.y = -Zc.y;
            float2 Fk = make_float2(0.5f * (Zt.x + Zc.x), 0.5f * (Zt.y + Zc.y));
            float2 Fv = make_float2(0.5f * (Zt.y - Zc.y), -0.5f * (Zt.x - Zc.x));
            float2 P = cmul(Fk, Fv);
            accr[h].x += P.x; accr[h].y += P.y;
        }
    }
#pragma unroll
    for (int h = 0; h < 4; ++h) {
        const int j = tid + (h << 8);
        atomicAdd(&Fs[(size_t)b * D + j].x, accr[h].x);
        atomicAdd(&Fs[(size_t)b * D + j].y, accr[h].y);
    }
}

__global__ __launch_bounds__(256) void retrieve_kernel(
    const __half* __restrict__ Q, const __half* __restrict__ R,
    const float2* __restrict__ Fs, const float* __restrict__ x, float* __restrict__ out)
{
    __shared__ __align__(16) float2 bufA[D];
    __shared__ __align__(16) float2 bufB[D];
    __shared__ __align__(16) float2 Wt[D / 2];
    const int tid = threadIdx.x;
    build_twiddles(Wt, tid);

    const int row = blockIdx.x;
    const int b = row >> 12;
    const size_t base = (size_t)row * D;

#pragma unroll
    for (int h = 0; h < 4; ++h) {
        const int j = tid + (h << 8);
        bufA[j] = make_float2(__half2float(Q[base + j]), __half2float(R[base + j]));
    }
    fft1024(bufA, bufB, Wt, 1.0f, tid);

#pragma unroll
    for (int h = 0; h < 4; ++h) {
        const int j = tid + (h << 8);
        const int j2 = (D - j) & (D - 1);
        float2 Zt = bufA[j];
        float2 Zc = bufA[j2]; Zc.y = -Zc.y;
        float2 Fq = make_float2(0.5f * (Zt.x + Zc.x), 0.5f * (Zt.y + Zc.y));
        float2 Fr = make_float2(0.5f * (Zt.y - Zc.y), -0.5f * (Zt.x - Zc.x));
        float2 g  = make_float2(Fq.x - (Fr.x * Fr.x + Fr.y * Fr.y), -Fq.y);
        float2 Ff = Fs[(size_t)b * D + j];
        bufB[j] = cmul(Ff, g);
    }
    fft1024(bufB, bufA, Wt, -1.0f, tid);

    const float inv = 1.0f / (float)D;
#pragma unroll
    for (int h = 0; h < 4; ++h) {
        const int j = tid + (h << 8);
        out[base + j] = x[base + j] + bufB[j].x * inv;
    }
}

extern "C" void kernel_launch(void* const* d_in, const int* in_sizes, int n_in,
                              void* d_out, int out_size, void* d_ws, size_t ws_size,
                              hipStream_t stream) {
    const float* x  = (const float*)d_in[0];
    const float* Wq = (const float*)d_in[1];
    const float* bq = (const float*)d_in[2];
    const float* Wk = (const float*)d_in[3];
    const float* bk = (const float*)d_in[4];
    const float* Wv = (const float*)d_in[5];
    const float* bv = (const float*)d_in[6];
    const float* Wr = (const float*)d_in[7];
    const float* br = (const float*)d_in[8];
    float* out = (float*)d_out;

    // ws: P0 (32MB fp16), P1 (32MB fp16), Fs (32KB) — proven layout
    __half* P0 = (__half*)d_ws;
    __half* P1 = (__half*)((char*)d_ws + (size_t)NROWS * D * 2);
    float2* Fs = (float2*)((char*)d_ws + (size_t)NROWS * D * 4);

    // d_out doubles as fp16 scratch until the final kernel rewrites all of it:
    // Xh [0,32MB), Whk/Whv/Whq/Whr 2MB each at 32MB+
    __half* Xh  = (__half*)d_out;
    __half* Whk = (__half*)d_out + (size_t)16 * 1024 * 1024;
    __half* Whv = Whk + (size_t)1024 * 1024;
    __half* Whq = Whv + (size_t)1024 * 1024;
    __half* Whr = Whq + (size_t)1024 * 1024;

    convert_all<<<16384 + 4 * 1024, 256, 0, stream>>>(
        x, Wk, Wv, Wq, Wr, Xh, Whk, Whv, Whq, Whr);

    hipMemsetAsync(Fs, 0, (size_t)BATCH * D * sizeof(float2), stream);

    dim3 ggrid(1024 / 128, NROWS / 128, 2);
    gemm_mfma<<<ggrid, 256, 0, stream>>>(Xh, Whk, bk, P0, Whv, bv, P1);
    bind_accum_kernel<<<NROWS / ROWS_PER_BLOCK, 256, 0, stream>>>(P0, P1, Fs);
    gemm_mfma<<<ggrid, 256, 0, stream>>>(Xh, Whq, bq, P0, Whr, br, P1);
    retrieve_kernel<<<NROWS, 256, 0, stream>>>(P0, P1, Fs, x, out);
}

// Round 3
// 496.699 us; speedup vs baseline: 4.6314x; 1.1554x over previous
//
#include <hip/hip_runtime.h>
#include <hip/hip_fp16.h>

#define D 1024
#define LOG2D 10
#define S_LEN 4096
#define BATCH 4
#define NROWS (BATCH * S_LEN) /* 16384 */
#define PI_F 3.14159265358979323846f

// padded LDS slot: one float2 pad per 16 -> breaks power-of-2 bank strides
#define SLOT(p) ((p) + ((p) >> 4))
#define FBUF 1088   /* SLOT(1023)+1 = 1087, rounded */
#define NTW 341     /* 1+4+16+64+256 per-stage twiddles */

typedef _Float16 f16x8 __attribute__((ext_vector_type(8)));
typedef float f32x4 __attribute__((ext_vector_type(4)));

__device__ __forceinline__ float2 cmul(float2 a, float2 b) {
    return make_float2(a.x * b.x - a.y * b.y, a.x * b.y + a.y * b.x);
}

__device__ __forceinline__ float fast_tanh(float v) {
    float e = __expf(2.0f * v);
    return 1.0f - 2.0f * __builtin_amdgcn_rcpf(e + 1.0f);
}

__device__ __forceinline__ void g2lds16(const void* g, void* l) {
    __builtin_amdgcn_global_load_lds(
        (const __attribute__((address_space(1))) unsigned int*)g,
        (__attribute__((address_space(3))) unsigned int*)l, 16, 0, 0);
}

// ---------------- fp32 -> fp16 conversion (x and the 4 weight matrices) ----
__global__ __launch_bounds__(256) void convert_all(
    const float* __restrict__ x,
    const float* __restrict__ w0, const float* __restrict__ w1,
    const float* __restrict__ w2, const float* __restrict__ w3,
    __half* __restrict__ xh,
    __half* __restrict__ h0, __half* __restrict__ h1,
    __half* __restrict__ h2, __half* __restrict__ h3)
{
    const int b = blockIdx.x;
    const float* s;
    __half* d;
    int li;
    if (b < 16384) { s = x; d = xh; li = b; }
    else {
        int t = b - 16384;
        int r = t >> 10;
        li = t & 1023;
        s = (r == 0) ? w0 : (r == 1) ? w1 : (r == 2) ? w2 : w3;
        d = (r == 0) ? h0 : (r == 1) ? h1 : (r == 2) ? h2 : h3;
    }
    const int idx = li * 256 + threadIdx.x;  // float4 index
    float4 v = ((const float4*)s)[idx];
    __half2 lo = __floats2half2_rn(v.x, v.y);
    __half2 hi = __floats2half2_rn(v.z, v.w);
    ((__half2*)d)[2 * idx + 0] = lo;
    ((__half2*)d)[2 * idx + 1] = hi;
}

// ---------------- MFMA GEMM: O = tanh(Xh * Wh^T + bias), fp16 out ----------
__global__ __launch_bounds__(256) void gemm_mfma(
    const __half* __restrict__ Xh,
    const __half* __restrict__ WA, const float* __restrict__ bA, __half* __restrict__ OA,
    const __half* __restrict__ WB, const float* __restrict__ bB, __half* __restrict__ OB)
{
    const __half* W    = blockIdx.z ? WB : WA;
    const float* bias  = blockIdx.z ? bB : bA;
    __half* O          = blockIdx.z ? OB : OA;

    const int m0 = blockIdx.y * 128;
    const int n0 = blockIdx.x * 128;

    __shared__ __align__(16) __half As[128 * 32];
    __shared__ __align__(16) __half Bs[128 * 32];

    const int tid = threadIdx.x;
    const int wave = tid >> 6;
    const int lane = tid & 63;

    const int srow = lane >> 2;
    const int schunk = (lane & 3) ^ ((lane >> 3) & 3);

    const __half* gA[2];
    const __half* gB[2];
    __half* lA[2];
    __half* lB[2];
#pragma unroll
    for (int c = 0; c < 2; ++c) {
        const int rg = (wave * 2 + c) * 16 + srow;
        gA[c] = Xh + (size_t)(m0 + rg) * 1024 + schunk * 8;
        gB[c] = W  + (size_t)(n0 + rg) * 1024 + schunk * 8;
        lA[c] = As + (wave * 2 + c) * 512;
        lB[c] = Bs + (wave * 2 + c) * 512;
    }

    const int wm = (wave & 1) * 64;
    const int wn = (wave >> 1) * 64;
    const int quad = lane >> 4;
    const int l15 = lane & 15;

    int aoff[4], boff[4];
#pragma unroll
    for (int i = 0; i < 4; ++i) {
        const int Ra = wm + i * 16 + l15;
        aoff[i] = Ra * 32 + (quad ^ ((Ra >> 1) & 3)) * 8;
        const int Rb = wn + i * 16 + l15;
        boff[i] = Rb * 32 + (quad ^ ((Rb >> 1) & 3)) * 8;
    }

    f32x4 acc[4][4];
#pragma unroll
    for (int i = 0; i < 4; ++i)
#pragma unroll
        for (int j = 0; j < 4; ++j) acc[i][j] = (f32x4){0.f, 0.f, 0.f, 0.f};

    for (int kt = 0; kt < 32; ++kt) {
        const int kh = kt * 32;
        __syncthreads();
        g2lds16(gA[0] + kh, lA[0]);
        g2lds16(gA[1] + kh, lA[1]);
        g2lds16(gB[0] + kh, lB[0]);
        g2lds16(gB[1] + kh, lB[1]);
        __syncthreads();

        f16x8 af[4], bf[4];
#pragma unroll
        for (int i = 0; i < 4; ++i) af[i] = *(const f16x8*)(As + aoff[i]);
#pragma unroll
        for (int j = 0; j < 4; ++j) bf[j] = *(const f16x8*)(Bs + boff[j]);
#pragma unroll
        for (int i = 0; i < 4; ++i)
#pragma unroll
            for (int j = 0; j < 4; ++j)
                acc[i][j] = __builtin_amdgcn_mfma_f32_16x16x32_f16(af[i], bf[j], acc[i][j], 0, 0, 0);
    }

#pragma unroll
    for (int j = 0; j < 4; ++j) {
        const int n = n0 + wn + j * 16 + l15;
        const float bv = bias[n];
#pragma unroll
        for (int i = 0; i < 4; ++i) {
            const int mbase = m0 + wm + i * 16 + quad * 4;
#pragma unroll
            for (int r = 0; r < 4; ++r) {
                float v = fast_tanh(acc[i][j][r] + bv);
                O[(size_t)(mbase + r) * 1024 + n] = __float2half(v);
            }
        }
    }
}

// ---------------- radix-4 Stockham FFT, length 1024, 256 threads ----------
// Per-stage twiddle tables, concatenated: stage s (m=4^s) at offset
// (4^s-1)/3, entries W_1024^{k*256/m} = exp(-i*pi*k/(2m)), k in [0,m).
__device__ __forceinline__ void build_twiddles_r4(float2* Wts, int tid) {
    for (int j = tid; j < NTW; j += 256) {
        int k, m;
        if (j == 0)      { k = 0;      m = 1;   }
        else if (j < 5)  { k = j - 1;  m = 4;   }
        else if (j < 21) { k = j - 5;  m = 16;  }
        else if (j < 85) { k = j - 21; m = 64;  }
        else             { k = j - 85; m = 256; }
        float ang = PI_F * (float)k / (2.0f * (float)m);
        Wts[j] = make_float2(cosf(ang), -sinf(ang));
    }
}

// Input in bufA (padded slots), result in bufB (padded slots).
// dir=+1 forward, dir=-1 inverse (unscaled).
__device__ void fft1024_r4(float2* bufA, float2* bufB, const float2* Wts,
                           float dir, int tid) {
    float2* src = bufA;
    float2* dst = bufB;
    int m = 1;
#pragma unroll
    for (int s = 0; s < 5; ++s) {
        __syncthreads();
        const int k = tid & (m - 1);
        const int jb = tid >> (2 * s);
        float2 x0 = src[SLOT(tid)];
        float2 x1 = src[SLOT(tid + 256)];
        float2 x2 = src[SLOT(tid + 512)];
        float2 x3 = src[SLOT(tid + 768)];
        float2 y1, y2, y3;
        if (s == 0) { y1 = x1; y2 = x2; y3 = x3; }
        else {
            const int soff = (m - 1) / 3;  // 0,1,5,21,85
            float2 t1 = Wts[soff + k];
            t1.y *= dir;
            float2 t2 = cmul(t1, t1);
            float2 t3 = cmul(t1, t2);
            y1 = cmul(x1, t1);
            y2 = cmul(x2, t2);
            y3 = cmul(x3, t3);
        }
        float2 a = make_float2(x0.x + y2.x, x0.y + y2.y);
        float2 b = make_float2(x0.x - y2.x, x0.y - y2.y);
        float2 c = make_float2(y1.x + y3.x, y1.y + y3.y);
        float2 d = make_float2(y1.x - y3.x, y1.y - y3.y);
        float2 e = make_float2(dir * d.y, -dir * d.x);  // -i*d fwd, +i*d inv
        const int o = (jb << (2 * s + 2)) + k;
        dst[SLOT(o)]         = make_float2(a.x + c.x, a.y + c.y);
        dst[SLOT(o + m)]     = make_float2(b.x + e.x, b.y + e.y);
        dst[SLOT(o + 2 * m)] = make_float2(a.x - c.x, a.y - c.y);
        dst[SLOT(o + 3 * m)] = make_float2(b.x - e.x, b.y - e.y);
        float2* t = src; src = dst; dst = t;
        m <<= 2;
    }
    __syncthreads();
}

// Per row: Z = FFT(k + i*v); Fk,Fv via Hermitian split; accumulate Fk*Fv into Fs[b].
#define ROWS_PER_BLOCK 8
__global__ __launch_bounds__(256) void bind_accum_kernel(
    const __half* __restrict__ K, const __half* __restrict__ V, float2* __restrict__ Fs)
{
    __shared__ __align__(16) float2 bufA[FBUF];
    __shared__ __align__(16) float2 bufB[FBUF];
    __shared__ __align__(16) float2 Wts[NTW];
    const int tid = threadIdx.x;
    build_twiddles_r4(Wts, tid);

    const int row0 = blockIdx.x * ROWS_PER_BLOCK;
    const int b = row0 >> 12;

    float2 accr[4];
#pragma unroll
    for (int h = 0; h < 4; ++h) accr[h] = make_float2(0.f, 0.f);

    for (int r = 0; r < ROWS_PER_BLOCK; ++r) {
        const size_t base = (size_t)(row0 + r) * D;
        // fft's leading/trailing barriers order all LDS phases here
#pragma unroll
        for (int h = 0; h < 4; ++h) {
            const int j = tid + (h << 8);
            bufA[SLOT(j)] = make_float2(__half2float(K[base + j]), __half2float(V[base + j]));
        }
        fft1024_r4(bufA, bufB, Wts, 1.0f, tid);  // Z in bufB
#pragma unroll
        for (int h = 0; h < 4; ++h) {
            const int j = tid + (h << 8);
            const int j2 = (D - j) & (D - 1);
            float2 Zt = bufB[SLOT(j)];
            float2 Zc = bufB[SLOT(j2)]; Zc.y = -Zc.y;
            float2 Fk = make_float2(0.5f * (Zt.x + Zc.x), 0.5f * (Zt.y + Zc.y));
            float2 Fv = make_float2(0.5f * (Zt.y - Zc.y), -0.5f * (Zt.x - Zc.x));
            float2 P = cmul(Fk, Fv);
            accr[h].x += P.x; accr[h].y += P.y;
        }
    }
#pragma unroll
    for (int h = 0; h < 4; ++h) {
        const int j = tid + (h << 8);
        atomicAdd(&Fs[(size_t)b * D + j].x, accr[h].x);
        atomicAdd(&Fs[(size_t)b * D + j].y, accr[h].y);
    }
}

// Per row: Z = FFT(q + i*r); g = conj(Fq) - |Fr|^2; y = ifft(Fs*g); out = x + Re(y)/D.
__global__ __launch_bounds__(256) void retrieve_kernel(
    const __half* __restrict__ Q, const __half* __restrict__ R,
    const float2* __restrict__ Fs, const float* __restrict__ x, float* __restrict__ out)
{
    __shared__ __align__(16) float2 bufA[FBUF];
    __shared__ __align__(16) float2 bufB[FBUF];
    __shared__ __align__(16) float2 Wts[NTW];
    const int tid = threadIdx.x;
    build_twiddles_r4(Wts, tid);

    const int row = blockIdx.x;
    const int b = row >> 12;
    const size_t base = (size_t)row * D;

#pragma unroll
    for (int h = 0; h < 4; ++h) {
        const int j = tid + (h << 8);
        bufA[SLOT(j)] = make_float2(__half2float(Q[base + j]), __half2float(R[base + j]));
    }
    fft1024_r4(bufA, bufB, Wts, 1.0f, tid);  // Z in bufB

#pragma unroll
    for (int h = 0; h < 4; ++h) {
        const int j = tid + (h << 8);
        const int j2 = (D - j) & (D - 1);
        float2 Zt = bufB[SLOT(j)];
        float2 Zc = bufB[SLOT(j2)]; Zc.y = -Zc.y;
        float2 Fq = make_float2(0.5f * (Zt.x + Zc.x), 0.5f * (Zt.y + Zc.y));
        float2 Fr = make_float2(0.5f * (Zt.y - Zc.y), -0.5f * (Zt.x - Zc.x));
        float2 g  = make_float2(Fq.x - (Fr.x * Fr.x + Fr.y * Fr.y), -Fq.y);
        float2 Ff = Fs[(size_t)b * D + j];
        bufA[SLOT(j)] = cmul(Ff, g);
    }
    fft1024_r4(bufA, bufB, Wts, -1.0f, tid);  // y in bufB (unscaled)

    const float inv = 1.0f / (float)D;
#pragma unroll
    for (int h = 0; h < 4; ++h) {
        const int j = tid + (h << 8);
        out[base + j] = x[base + j] + bufB[SLOT(j)].x * inv;
    }
}

extern "C" void kernel_launch(void* const* d_in, const int* in_sizes, int n_in,
                              void* d_out, int out_size, void* d_ws, size_t ws_size,
                              hipStream_t stream) {
    const float* x  = (const float*)d_in[0];
    const float* Wq = (const float*)d_in[1];
    const float* bq = (const float*)d_in[2];
    const float* Wk = (const float*)d_in[3];
    const float* bk = (const float*)d_in[4];
    const float* Wv = (const float*)d_in[5];
    const float* bv = (const float*)d_in[6];
    const float* Wr = (const float*)d_in[7];
    const float* br = (const float*)d_in[8];
    float* out = (float*)d_out;

    // ws: P0 (32MB fp16), P1 (32MB fp16), Fs (32KB)
    __half* P0 = (__half*)d_ws;
    __half* P1 = (__half*)((char*)d_ws + (size_t)NROWS * D * 2);
    float2* Fs = (float2*)((char*)d_ws + (size_t)NROWS * D * 4);

    // d_out doubles as fp16 scratch until the final kernel rewrites all of it
    __half* Xh  = (__half*)d_out;
    __half* Whk = (__half*)d_out + (size_t)16 * 1024 * 1024;
    __half* Whv = Whk + (size_t)1024 * 1024;
    __half* Whq = Whv + (size_t)1024 * 1024;
    __half* Whr = Whq + (size_t)1024 * 1024;

    convert_all<<<16384 + 4 * 1024, 256, 0, stream>>>(
        x, Wk, Wv, Wq, Wr, Xh, Whk, Whv, Whq, Whr);

    hipMemsetAsync(Fs, 0, (size_t)BATCH * D * sizeof(float2), stream);

    dim3 ggrid(1024 / 128, NROWS / 128, 2);
    gemm_mfma<<<ggrid, 256, 0, stream>>>(Xh, Whk, bk, P0, Whv, bv, P1);
    bind_accum_kernel<<<NROWS / ROWS_PER_BLOCK, 256, 0, stream>>>(P0, P1, Fs);
    gemm_mfma<<<ggrid, 256, 0, stream>>>(Xh, Whq, bq, P0, Whr, br, P1);
    retrieve_kernel<<<NROWS, 256, 0, stream>>>(P0, P1, Fs, x, out);
}

// Round 4
// 472.312 us; speedup vs baseline: 4.8706x; 1.0516x over previous
//
#include <hip/hip_runtime.h>
#include <hip/hip_fp16.h>

#define D 1024
#define LOG2D 10
#define S_LEN 4096
#define BATCH 4
#define NROWS (BATCH * S_LEN) /* 16384 */
#define PI_F 3.14159265358979323846f

// padded LDS slot: one float2 pad per 16 -> breaks power-of-2 bank strides
#define SLOT(p) ((p) + ((p) >> 4))
#define FBUF 1088
#define NTW 341

typedef _Float16 f16x8 __attribute__((ext_vector_type(8)));
typedef float f32x4 __attribute__((ext_vector_type(4)));

__device__ __forceinline__ float2 cmul(float2 a, float2 b) {
    return make_float2(a.x * b.x - a.y * b.y, a.x * b.y + a.y * b.x);
}

__device__ __forceinline__ float fast_tanh(float v) {
    float e = __expf(2.0f * v);
    return 1.0f - 2.0f * __builtin_amdgcn_rcpf(e + 1.0f);
}

__device__ __forceinline__ void g2lds16(const void* g, void* l) {
    __builtin_amdgcn_global_load_lds(
        (const __attribute__((address_space(1))) unsigned int*)g,
        (__attribute__((address_space(3))) unsigned int*)l, 16, 0, 0);
}

// ---------------- fp32 -> fp16 conversion (x and the 4 weight matrices) ----
__global__ __launch_bounds__(256) void convert_all(
    const float* __restrict__ x,
    const float* __restrict__ w0, const float* __restrict__ w1,
    const float* __restrict__ w2, const float* __restrict__ w3,
    __half* __restrict__ xh,
    __half* __restrict__ h0, __half* __restrict__ h1,
    __half* __restrict__ h2, __half* __restrict__ h3)
{
    const int b = blockIdx.x;
    const float* s;
    __half* d;
    int li;
    if (b < 16384) { s = x; d = xh; li = b; }
    else {
        int t = b - 16384;
        int r = t >> 10;
        li = t & 1023;
        s = (r == 0) ? w0 : (r == 1) ? w1 : (r == 2) ? w2 : w3;
        d = (r == 0) ? h0 : (r == 1) ? h1 : (r == 2) ? h2 : h3;
    }
    const int idx = li * 256 + threadIdx.x;  // float4 index
    float4 v = ((const float4*)s)[idx];
    __half2 lo = __floats2half2_rn(v.x, v.y);
    __half2 hi = __floats2half2_rn(v.z, v.w);
    ((__half2*)d)[2 * idx + 0] = lo;
    ((__half2*)d)[2 * idx + 1] = hi;
}

// ------- Fused dual MFMA GEMM: O{0,1} = tanh(Xh * W{0,1}^T + b{0,1}) -------
// 128x128 tile, BK=32, 256 thr. A staged once, both B tiles staged; 32 MFMA
// per wave per k-tile. XCD-swizzled block mapping: idx&7 = XCD, each XCD owns
// 16 contiguous m-panels, n fastest -> A-panel + W tiles stay in that XCD's L2.
__global__ __launch_bounds__(256, 2) void gemm_mfma2(
    const __half* __restrict__ Xh,
    const __half* __restrict__ W0, const float* __restrict__ b0, __half* __restrict__ O0,
    const __half* __restrict__ W1, const float* __restrict__ b1, __half* __restrict__ O1)
{
    const int idx = blockIdx.x;
    const int xcd = idx & 7;
    const int j = idx >> 3;           // 0..127
    const int n0 = (j & 7) * 128;
    const int m0 = (xcd * 16 + (j >> 3)) * 128;

    __shared__ __align__(16) __half As[128 * 32];
    __shared__ __align__(16) __half B0s[128 * 32];
    __shared__ __align__(16) __half B1s[128 * 32];

    const int tid = threadIdx.x;
    const int wave = tid >> 6;
    const int lane = tid & 63;

    const int srow = lane >> 2;                         // row in 16-row group
    const int schunk = (lane & 3) ^ ((lane >> 3) & 3);  // swizzled 16B chunk

    const __half* gA[2];
    const __half* gB0[2];
    const __half* gB1[2];
    __half* lA[2];
    __half* lB0[2];
    __half* lB1[2];
#pragma unroll
    for (int c = 0; c < 2; ++c) {
        const int rg = (wave * 2 + c) * 16 + srow;
        gA[c]  = Xh + (size_t)(m0 + rg) * 1024 + schunk * 8;
        gB0[c] = W0 + (size_t)(n0 + rg) * 1024 + schunk * 8;
        gB1[c] = W1 + (size_t)(n0 + rg) * 1024 + schunk * 8;
        lA[c]  = As  + (wave * 2 + c) * 512;
        lB0[c] = B0s + (wave * 2 + c) * 512;
        lB1[c] = B1s + (wave * 2 + c) * 512;
    }

    const int wm = (wave & 1) * 64;
    const int wn = (wave >> 1) * 64;
    const int quad = lane >> 4;
    const int l15 = lane & 15;

    int aoff[4], boff[4];
#pragma unroll
    for (int i = 0; i < 4; ++i) {
        const int Ra = wm + i * 16 + l15;
        aoff[i] = Ra * 32 + (quad ^ ((Ra >> 1) & 3)) * 8;
        const int Rb = wn + i * 16 + l15;
        boff[i] = Rb * 32 + (quad ^ ((Rb >> 1) & 3)) * 8;
    }

    f32x4 acc0[4][4], acc1[4][4];
#pragma unroll
    for (int i = 0; i < 4; ++i)
#pragma unroll
        for (int jj = 0; jj < 4; ++jj) {
            acc0[i][jj] = (f32x4){0.f, 0.f, 0.f, 0.f};
            acc1[i][jj] = (f32x4){0.f, 0.f, 0.f, 0.f};
        }

    for (int kt = 0; kt < 32; ++kt) {
        const int kh = kt * 32;
        __syncthreads();
        g2lds16(gA[0] + kh, lA[0]);
        g2lds16(gA[1] + kh, lA[1]);
        g2lds16(gB0[0] + kh, lB0[0]);
        g2lds16(gB0[1] + kh, lB0[1]);
        g2lds16(gB1[0] + kh, lB1[0]);
        g2lds16(gB1[1] + kh, lB1[1]);
        __syncthreads();

        f16x8 af[4], bf0[4], bf1[4];
#pragma unroll
        for (int i = 0; i < 4; ++i) af[i] = *(const f16x8*)(As + aoff[i]);
#pragma unroll
        for (int jj = 0; jj < 4; ++jj) {
            bf0[jj] = *(const f16x8*)(B0s + boff[jj]);
            bf1[jj] = *(const f16x8*)(B1s + boff[jj]);
        }
#pragma unroll
        for (int i = 0; i < 4; ++i)
#pragma unroll
            for (int jj = 0; jj < 4; ++jj) {
                acc0[i][jj] = __builtin_amdgcn_mfma_f32_16x16x32_f16(af[i], bf0[jj], acc0[i][jj], 0, 0, 0);
                acc1[i][jj] = __builtin_amdgcn_mfma_f32_16x16x32_f16(af[i], bf1[jj], acc1[i][jj], 0, 0, 0);
            }
    }

    // epilogue: C/D frag mapping col=lane&15, row=quad*4+reg
#pragma unroll
    for (int jj = 0; jj < 4; ++jj) {
        const int n = n0 + wn + jj * 16 + l15;
        const float bv0 = b0[n];
        const float bv1 = b1[n];
#pragma unroll
        for (int i = 0; i < 4; ++i) {
            const int mbase = m0 + wm + i * 16 + quad * 4;
#pragma unroll
            for (int r = 0; r < 4; ++r) {
                O0[(size_t)(mbase + r) * 1024 + n] = __float2half(fast_tanh(acc0[i][jj][r] + bv0));
                O1[(size_t)(mbase + r) * 1024 + n] = __float2half(fast_tanh(acc1[i][jj][r] + bv1));
            }
        }
    }
}

// ---------------- radix-4 Stockham FFT, length 1024, 256 threads ----------
__device__ __forceinline__ void build_twiddles_r4(float2* Wts, int tid) {
    for (int j = tid; j < NTW; j += 256) {
        int k, m;
        if (j == 0)      { k = 0;      m = 1;   }
        else if (j < 5)  { k = j - 1;  m = 4;   }
        else if (j < 21) { k = j - 5;  m = 16;  }
        else if (j < 85) { k = j - 21; m = 64;  }
        else             { k = j - 85; m = 256; }
        float ang = PI_F * (float)k / (2.0f * (float)m);
        Wts[j] = make_float2(cosf(ang), -sinf(ang));
    }
}

__device__ void fft1024_r4(float2* bufA, float2* bufB, const float2* Wts,
                           float dir, int tid) {
    float2* src = bufA;
    float2* dst = bufB;
    int m = 1;
#pragma unroll
    for (int s = 0; s < 5; ++s) {
        __syncthreads();
        const int k = tid & (m - 1);
        const int jb = tid >> (2 * s);
        float2 x0 = src[SLOT(tid)];
        float2 x1 = src[SLOT(tid + 256)];
        float2 x2 = src[SLOT(tid + 512)];
        float2 x3 = src[SLOT(tid + 768)];
        float2 y1, y2, y3;
        if (s == 0) { y1 = x1; y2 = x2; y3 = x3; }
        else {
            const int soff = (m - 1) / 3;
            float2 t1 = Wts[soff + k];
            t1.y *= dir;
            float2 t2 = cmul(t1, t1);
            float2 t3 = cmul(t1, t2);
            y1 = cmul(x1, t1);
            y2 = cmul(x2, t2);
            y3 = cmul(x3, t3);
        }
        float2 a = make_float2(x0.x + y2.x, x0.y + y2.y);
        float2 b = make_float2(x0.x - y2.x, x0.y - y2.y);
        float2 c = make_float2(y1.x + y3.x, y1.y + y3.y);
        float2 d = make_float2(y1.x - y3.x, y1.y - y3.y);
        float2 e = make_float2(dir * d.y, -dir * d.x);
        const int o = (jb << (2 * s + 2)) + k;
        dst[SLOT(o)]         = make_float2(a.x + c.x, a.y + c.y);
        dst[SLOT(o + m)]     = make_float2(b.x + e.x, b.y + e.y);
        dst[SLOT(o + 2 * m)] = make_float2(a.x - c.x, a.y - c.y);
        dst[SLOT(o + 3 * m)] = make_float2(b.x - e.x, b.y - e.y);
        float2* t = src; src = dst; dst = t;
        m <<= 2;
    }
    __syncthreads();
}

#define ROWS_PER_BLOCK 8
__global__ __launch_bounds__(256) void bind_accum_kernel(
    const __half* __restrict__ K, const __half* __restrict__ V, float2* __restrict__ Fs)
{
    __shared__ __align__(16) float2 bufA[FBUF];
    __shared__ __align__(16) float2 bufB[FBUF];
    __shared__ __align__(16) float2 Wts[NTW];
    const int tid = threadIdx.x;
    build_twiddles_r4(Wts, tid);

    const int row0 = blockIdx.x * ROWS_PER_BLOCK;
    const int b = row0 >> 12;

    float2 accr[4];
#pragma unroll
    for (int h = 0; h < 4; ++h) accr[h] = make_float2(0.f, 0.f);

    for (int r = 0; r < ROWS_PER_BLOCK; ++r) {
        const size_t base = (size_t)(row0 + r) * D;
#pragma unroll
        for (int h = 0; h < 4; ++h) {
            const int j = tid + (h << 8);
            bufA[SLOT(j)] = make_float2(__half2float(K[base + j]), __half2float(V[base + j]));
        }
        fft1024_r4(bufA, bufB, Wts, 1.0f, tid);  // Z in bufB
#pragma unroll
        for (int h = 0; h < 4; ++h) {
            const int j = tid + (h << 8);
            const int j2 = (D - j) & (D - 1);
            float2 Zt = bufB[SLOT(j)];
            float2 Zc = bufB[SLOT(j2)]; Zc.y = -Zc.y;
            float2 Fk = make_float2(0.5f * (Zt.x + Zc.x), 0.5f * (Zt.y + Zc.y));
            float2 Fv = make_float2(0.5f * (Zt.y - Zc.y), -0.5f * (Zt.x - Zc.x));
            float2 P = cmul(Fk, Fv);
            accr[h].x += P.x; accr[h].y += P.y;
        }
    }
#pragma unroll
    for (int h = 0; h < 4; ++h) {
        const int j = tid + (h << 8);
        atomicAdd(&Fs[(size_t)b * D + j].x, accr[h].x);
        atomicAdd(&Fs[(size_t)b * D + j].y, accr[h].y);
    }
}

__global__ __launch_bounds__(256) void retrieve_kernel(
    const __half* __restrict__ Q, const __half* __restrict__ R,
    const float2* __restrict__ Fs, const float* __restrict__ x, float* __restrict__ out)
{
    __shared__ __align__(16) float2 bufA[FBUF];
    __shared__ __align__(16) float2 bufB[FBUF];
    __shared__ __align__(16) float2 Wts[NTW];
    const int tid = threadIdx.x;
    build_twiddles_r4(Wts, tid);

    const int row = blockIdx.x;
    const int b = row >> 12;
    const size_t base = (size_t)row * D;

#pragma unroll
    for (int h = 0; h < 4; ++h) {
        const int j = tid + (h << 8);
        bufA[SLOT(j)] = make_float2(__half2float(Q[base + j]), __half2float(R[base + j]));
    }
    fft1024_r4(bufA, bufB, Wts, 1.0f, tid);  // Z in bufB

#pragma unroll
    for (int h = 0; h < 4; ++h) {
        const int j = tid + (h << 8);
        const int j2 = (D - j) & (D - 1);
        float2 Zt = bufB[SLOT(j)];
        float2 Zc = bufB[SLOT(j2)]; Zc.y = -Zc.y;
        float2 Fq = make_float2(0.5f * (Zt.x + Zc.x), 0.5f * (Zt.y + Zc.y));
        float2 Fr = make_float2(0.5f * (Zt.y - Zc.y), -0.5f * (Zt.x - Zc.x));
        float2 g  = make_float2(Fq.x - (Fr.x * Fr.x + Fr.y * Fr.y), -Fq.y);
        float2 Ff = Fs[(size_t)b * D + j];
        bufA[SLOT(j)] = cmul(Ff, g);
    }
    fft1024_r4(bufA, bufB, Wts, -1.0f, tid);  // y in bufB (unscaled)

    const float inv = 1.0f / (float)D;
#pragma unroll
    for (int h = 0; h < 4; ++h) {
        const int j = tid + (h << 8);
        out[base + j] = x[base + j] + bufB[SLOT(j)].x * inv;
    }
}

extern "C" void kernel_launch(void* const* d_in, const int* in_sizes, int n_in,
                              void* d_out, int out_size, void* d_ws, size_t ws_size,
                              hipStream_t stream) {
    const float* x  = (const float*)d_in[0];
    const float* Wq = (const float*)d_in[1];
    const float* bq = (const float*)d_in[2];
    const float* Wk = (const float*)d_in[3];
    const float* bk = (const float*)d_in[4];
    const float* Wv = (const float*)d_in[5];
    const float* bv = (const float*)d_in[6];
    const float* Wr = (const float*)d_in[7];
    const float* br = (const float*)d_in[8];
    float* out = (float*)d_out;

    // ws: P0 (32MB fp16), P1 (32MB fp16), Fs (32KB)
    __half* P0 = (__half*)d_ws;
    __half* P1 = (__half*)((char*)d_ws + (size_t)NROWS * D * 2);
    float2* Fs = (float2*)((char*)d_ws + (size_t)NROWS * D * 4);

    // d_out doubles as fp16 scratch until the final kernel rewrites all of it
    __half* Xh  = (__half*)d_out;
    __half* Whk = (__half*)d_out + (size_t)16 * 1024 * 1024;
    __half* Whv = Whk + (size_t)1024 * 1024;
    __half* Whq = Whv + (size_t)1024 * 1024;
    __half* Whr = Whq + (size_t)1024 * 1024;

    convert_all<<<16384 + 4 * 1024, 256, 0, stream>>>(
        x, Wk, Wv, Wq, Wr, Xh, Whk, Whv, Whq, Whr);

    hipMemsetAsync(Fs, 0, (size_t)BATCH * D * sizeof(float2), stream);

    gemm_mfma2<<<1024, 256, 0, stream>>>(Xh, Whk, bk, P0, Whv, bv, P1);
    bind_accum_kernel<<<NROWS / ROWS_PER_BLOCK, 256, 0, stream>>>(P0, P1, Fs);
    gemm_mfma2<<<1024, 256, 0, stream>>>(Xh, Whq, bq, P0, Whr, br, P1);
    retrieve_kernel<<<NROWS, 256, 0, stream>>>(P0, P1, Fs, x, out);
}